// Round 16
// baseline (37.258 us; speedup 1.0000x reference)
//
#include <hip/hip_runtime.h>
#include <math.h>

#define NB 256
#define ND 2048
#define T_K 10.0f
#define PGRID 1024        // probe / filter grid (0.84 load-iters per thread)
#define FCAP 1024         // per-block LDS compaction capacity (float2 = 8 KB)

// ---------------------------------------------------------------------------
// K1 (PGRID blocks): blocks 0..255 compute stats row b; ALL blocks probe a
// queue sub-chunk (min d^2(c0,q), c0=(0,1)) -> u0part[b]. Block0 zeroes gcount.
// R15 post-mortem: 256-block streams are latency-bound (4 waves/CU, ~900cyc
// round trips); 1024 blocks = 4x the in-flight loads, ~1 iter/thread.
// ---------------------------------------------------------------------------
__global__ __launch_bounds__(256) void stats_probe_kernel(const float* __restrict__ feat,
                                                          const float* __restrict__ mus,
                                                          const float* __restrict__ sigmas,
                                                          float* __restrict__ stats,
                                                          float* __restrict__ u0part,
                                                          unsigned int* __restrict__ gcount,
                                                          int Q) {
    const int b = blockIdx.x, tid = threadIdx.x;
    const int lane = tid & 63, wid = tid >> 6;
    __shared__ float ls[4], lq[4];

    if (b == 0 && tid == 0) gcount[0] = 0u;

    // ---- stats for feature row b (blocks 0..255 only; block-uniform branch) ----
    if (b < NB) {
        const float4* row = (const float4*)(feat + (size_t)b * ND);
        float sum = 0.f, sumsq = 0.f;
#pragma unroll
        for (int i = 0; i < 2; ++i) {
            float4 v = row[tid + i * 256];
            sum   += v.x + v.y + v.z + v.w;
            sumsq += v.x * v.x + v.y * v.y + v.z * v.z + v.w * v.w;
        }
#pragma unroll
        for (int off = 32; off > 0; off >>= 1) {
            sum   += __shfl_down(sum, off, 64);
            sumsq += __shfl_down(sumsq, off, 64);
        }
        if (lane == 0) { ls[wid] = sum; lq[wid] = sumsq; }
        __syncthreads();
        if (tid == 0) {
            float S  = ls[0] + ls[1] + ls[2] + ls[3];
            float Q2 = lq[0] + lq[1] + lq[2] + lq[3];
            float mean = S / (float)ND;
            float var  = fmaxf((Q2 - S * mean) / (float)(ND - 1), 0.f);
            stats[b]      = mean;
            stats[NB + b] = sqrtf(var);
        }
        __syncthreads();            // ls/lq reused by probe reduce below
    }

    // ---- probe sub-chunk b ----
    const int nquad = Q >> 2;
    const int spq   = (nquad + PGRID - 1) / PGRID;
    const int qs    = b * spq;
    const int qe    = min(qs + spq, nquad);
    const float4* mu4 = (const float4*)mus;
    const float4* sg4 = (const float4*)sigmas;

    float best = INFINITY;
    for (int i = qs + tid; i < qe; i += 256) {
        float4 mu = mu4[i], sg = sg4[i];
        float s0 = sg.x - 1.f, s1 = sg.y - 1.f, s2e = sg.z - 1.f, s3 = sg.w - 1.f;
        best = fminf(best, fmaf(mu.x, mu.x, s0 * s0));
        best = fminf(best, fmaf(mu.y, mu.y, s1 * s1));
        best = fminf(best, fmaf(mu.z, mu.z, s2e * s2e));
        best = fminf(best, fmaf(mu.w, mu.w, s3 * s3));
    }
    if (b == 0) {                   // element tail (Q % 4)
        int q = nquad * 4 + tid;
        if (q < Q) {
            float dm = mus[q], ds = sigmas[q] - 1.f;
            best = fminf(best, fmaf(dm, dm, ds * ds));
        }
    }
#pragma unroll
    for (int off = 32; off > 0; off >>= 1)
        best = fminf(best, __shfl_down(best, off, 64));
    if (lane == 0) ls[wid] = best;
    __syncthreads();
    if (tid == 0)
        u0part[b] = fminf(fminf(ls[0], ls[1]), fminf(ls[2], ls[3]));
}

// ---------------------------------------------------------------------------
// K2 (PGRID blocks): redundant in-block threshold reduce (u0part[1024],
// stats[512] -> U0, R'^2; ~6KB L2-hot reads), then filter sub-chunk,
// LDS-compact survivors, ONE global atomicAdd per block, coalesced copy out.
// Exact bound: q prunable if d(c0,q) > U0 + 2R' (global winner q*, always
// kept, then beats q for every sample b: d(b,q) >= d(c0,q)-R' > U0+R' >=
// d(b,q*)). Threshold^2 inflated 1e-4 for fp32 rounding (absmax-validated).
// List order is atomic-nondeterministic; min over the set is order-invariant
// -> output deterministic.
// ---------------------------------------------------------------------------
__global__ __launch_bounds__(256) void filter_kernel(const float* __restrict__ mus,
                                                     const float* __restrict__ sigmas,
                                                     const float* __restrict__ stats,
                                                     const float* __restrict__ u0part,
                                                     unsigned int* __restrict__ gcount,
                                                     float2* __restrict__ glist,
                                                     int Q) {
    const int b = blockIdx.x, tid = threadIdx.x;
    const int lane = tid & 63, wid = tid >> 6;

    __shared__ float2 buf[FCAP];
    __shared__ float  ls[4], lq[4];
    __shared__ int    cnt;
    __shared__ unsigned int gbase;

    // ---- threshold: U0 = min u0part[0..PGRID), R'^2 = max_b d^2(c0,b) ----
    {
        float u = INFINITY;
#pragma unroll
        for (int j = 0; j < PGRID / 256; ++j)
            u = fminf(u, u0part[tid + j * 256]);
        float mb = stats[tid], dsb = stats[NB + tid] - 1.f;
        float r2 = fmaf(mb, mb, dsb * dsb);
#pragma unroll
        for (int off = 32; off > 0; off >>= 1) {
            u  = fminf(u,  __shfl_down(u,  off, 64));
            r2 = fmaxf(r2, __shfl_down(r2, off, 64));
        }
        if (lane == 0) { ls[wid] = u; lq[wid] = r2; }
        if (tid == 0) cnt = 0;
    }
    __syncthreads();
    const float U0   = fminf(fminf(ls[0], ls[1]), fminf(ls[2], ls[3]));
    const float R2   = fmaxf(fmaxf(lq[0], lq[1]), fmaxf(lq[2], lq[3]));
    const float thr  = sqrtf(U0) + 2.f * sqrtf(R2);
    const float thr2 = thr * thr * 1.0001f + 1e-12f;

    const int nquad = Q >> 2;
    const int spq   = (nquad + PGRID - 1) / PGRID;
    const int qs    = b * spq;
    const int qe    = min(qs + spq, nquad);
    const float4* mu4 = (const float4*)mus;
    const float4* sg4 = (const float4*)sigmas;

    for (int base = qs; base < qe; base += 256) {
        __syncthreads();
        if (cnt > FCAP - 1024) {                      // safety flush (doesn't trigger at spq<=256)
            const int n = cnt;
            if (tid == 0) gbase = atomicAdd(gcount, (unsigned int)n);
            __syncthreads();
            for (int j = tid; j < n; j += 256) glist[gbase + j] = buf[j];
            __syncthreads();
            if (tid == 0) cnt = 0;
            __syncthreads();
        }
        const int i = base + tid;
        if (i < qe) {
            float4 mu = mu4[i], sg = sg4[i];
#define TESTK(MX, SX)                                                        \
            {                                                                \
                float dm = (MX), dss = (SX) - 1.f;                           \
                float dd = fmaf(dm, dm, dss * dss);                          \
                if (dd <= thr2) {                                            \
                    int p = atomicAdd(&cnt, 1);                              \
                    buf[p] = make_float2((MX), (SX));                        \
                }                                                            \
            }
            TESTK(mu.x, sg.x)
            TESTK(mu.y, sg.y)
            TESTK(mu.z, sg.z)
            TESTK(mu.w, sg.w)
        }
    }
    if (b == 0) {                                     // element tail (empty for Q=880880)
        int q = nquad * 4 + tid;
        if (q < Q) { TESTK(mus[q], sigmas[q]) }
    }
#undef TESTK

    __syncthreads();
    {
        const int n = cnt;
        if (tid == 0) gbase = atomicAdd(gcount, (unsigned int)n);
        __syncthreads();
        for (int j = tid; j < n; j += 256) glist[gbase + j] = buf[j];
    }
}

// ---------------------------------------------------------------------------
// K3 (NB blocks): block b = sample b. Lane-parallel scan of the compacted
// candidate list (~130KB, L2-resident after first touch per XCD), direct
// (m-mu)^2+(s-sg)^2, block min-reduce, fused T = exp(-k*sqrt(d2)) -> out[b].
// No partial matrix, no separate reduce kernel.
// ---------------------------------------------------------------------------
__global__ __launch_bounds__(256) void gather_scan_kernel(const float2* __restrict__ glist,
                                                          const unsigned int* __restrict__ gcount,
                                                          const float* __restrict__ stats,
                                                          float* __restrict__ out) {
    const int b = blockIdx.x, tid = threadIdx.x;
    const int lane = tid & 63, wid = tid >> 6;
    __shared__ float w[4];

    const float mb = stats[b], sb = stats[NB + b];
    const int n = (int)gcount[0];

    float best = INFINITY;
    for (int j = tid; j < n; j += 256) {
        float2 p = glist[j];
        float dm = mb - p.x, ds = sb - p.y;
        best = fminf(best, fmaf(dm, dm, ds * ds));
    }
#pragma unroll
    for (int off = 32; off > 0; off >>= 1)
        best = fminf(best, __shfl_down(best, off, 64));
    if (lane == 0) w[wid] = best;
    __syncthreads();
    if (tid == 0) {
        float m = fminf(fminf(w[0], w[1]), fminf(w[2], w[3]));
        out[b] = expf(-T_K * sqrtf(fmaxf(m, 0.f)));
    }
}

extern "C" void kernel_launch(void* const* d_in, const int* in_sizes, int n_in,
                              void* d_out, int out_size, void* d_ws, size_t ws_size,
                              hipStream_t stream) {
    const float* features = (const float*)d_in[0];
    // d_in[1]=labels, d_in[2]=pred, d_in[3]=confidence -- unused by reference
    const float* queue_mus    = (const float*)d_in[4];
    const float* queue_sigmas = (const float*)d_in[5];
    const int Q = in_sizes[4];

    float*        stats  = (float*)d_ws;                      // 2*NB floats
    float*        u0part = stats + 2 * NB;                    // PGRID floats
    unsigned int* gcount = (unsigned int*)(u0part + PGRID);   // 2 uints (align pad)
    float2*       glist  = (float2*)(gcount + 2);             // up to Q float2 (worst case)

    stats_probe_kernel<<<PGRID, 256, 0, stream>>>(features, queue_mus, queue_sigmas,
                                                  stats, u0part, gcount, Q);
    filter_kernel<<<PGRID, 256, 0, stream>>>(queue_mus, queue_sigmas, stats, u0part,
                                             gcount, glist, Q);
    gather_scan_kernel<<<NB, 256, 0, stream>>>(glist, gcount, stats, (float*)d_out);
}

// Round 17
// 22.525 us; speedup vs baseline: 1.6541x; 1.6541x over previous
//
#include <hip/hip_runtime.h>
#include <math.h>

#define NB 256
#define ND 2048
#define T_K 10.0f
#define PGRID 2048        // streaming grids: 8 blocks/CU -> full-TLP HBM streams
#define LDSCAP 2048       // compaction capacity (float2 = 16 KB LDS)

// ---------------------------------------------------------------------------
// K1 (PGRID blocks): blocks 0..255 also compute stats row b; ALL blocks probe
// their queue sub-chunk (min d^2(c0,q), c0=(0,1)) -> u0part[b].
// R13 post-mortem: 256-block stream = 1 wave/SIMD = ~27 dependent 900cyc
// round trips (~9us). 2048 blocks = one round-trip, fully latency-hidden.
// NO global atomics anywhere (R16 lesson: one contended gcount line cost 2x
// timed + 20ms profile outliers from cross-XCD RMW serialization).
// ---------------------------------------------------------------------------
__global__ __launch_bounds__(256) void stats_probe_kernel(const float* __restrict__ feat,
                                                          const float* __restrict__ mus,
                                                          const float* __restrict__ sigmas,
                                                          float* __restrict__ stats,
                                                          float* __restrict__ u0part,
                                                          int Q) {
    const int b = blockIdx.x, tid = threadIdx.x;
    const int lane = tid & 63, wid = tid >> 6;
    __shared__ float ls[4], lq[4];

    // ---- stats for feature row b (blocks 0..255 only; block-uniform branch) ----
    if (b < NB) {
        const float4* row = (const float4*)(feat + (size_t)b * ND);
        float sum = 0.f, sumsq = 0.f;
#pragma unroll
        for (int i = 0; i < 2; ++i) {
            float4 v = row[tid + i * 256];
            sum   += v.x + v.y + v.z + v.w;
            sumsq += v.x * v.x + v.y * v.y + v.z * v.z + v.w * v.w;
        }
#pragma unroll
        for (int off = 32; off > 0; off >>= 1) {
            sum   += __shfl_down(sum, off, 64);
            sumsq += __shfl_down(sumsq, off, 64);
        }
        if (lane == 0) { ls[wid] = sum; lq[wid] = sumsq; }
        __syncthreads();
        if (tid == 0) {
            float S  = ls[0] + ls[1] + ls[2] + ls[3];
            float Q2 = lq[0] + lq[1] + lq[2] + lq[3];
            float mean = S / (float)ND;
            float var  = fmaxf((Q2 - S * mean) / (float)(ND - 1), 0.f);
            stats[b]      = mean;
            stats[NB + b] = sqrtf(var);
        }
        __syncthreads();            // ls reused below
    }

    // ---- probe sub-chunk b ----
    const int nquad = Q >> 2;
    const int spq   = (nquad + PGRID - 1) / PGRID;
    const int qs    = b * spq;
    const int qe    = min(qs + spq, nquad);
    const float4* mu4 = (const float4*)mus;
    const float4* sg4 = (const float4*)sigmas;

    float best = INFINITY;
    for (int i = qs + tid; i < qe; i += 256) {
        float4 mu = mu4[i], sg = sg4[i];
        float s0 = sg.x - 1.f, s1 = sg.y - 1.f, s2e = sg.z - 1.f, s3 = sg.w - 1.f;
        best = fminf(best, fmaf(mu.x, mu.x, s0 * s0));
        best = fminf(best, fmaf(mu.y, mu.y, s1 * s1));
        best = fminf(best, fmaf(mu.z, mu.z, s2e * s2e));
        best = fminf(best, fmaf(mu.w, mu.w, s3 * s3));
    }
    if (b == 0) {                   // element tail (Q % 4)
        int q = nquad * 4 + tid;
        if (q < Q) {
            float dm = mus[q], ds = sigmas[q] - 1.f;
            best = fminf(best, fmaf(dm, dm, ds * ds));
        }
    }
#pragma unroll
    for (int off = 32; off > 0; off >>= 1)
        best = fminf(best, __shfl_down(best, off, 64));
    if (lane == 0) ls[wid] = best;
    __syncthreads();
    if (tid == 0)
        u0part[b] = fminf(fminf(ls[0], ls[1]), fminf(ls[2], ls[3]));
}

// ---------------------------------------------------------------------------
// K2 (PGRID blocks): in-block threshold reduce (u0part[2048] + stats, all
// L2-hot) -> filter sub-chunk -> LDS-compact survivors (~8/block) ->
// direct-form broadcast scan -> PRIVATE partial row (coalesced, atomic-free).
// Exact bound: q prunable if d(c0,q) > U0 + 2R'; the global winner q* always
// survives and then beats q for every sample (triangle ineq). thr^2 inflated
// 1e-4 for fp32 rounding. Survivor scan uses direct (m-mu)^2+(s-sg)^2 ->
// bit-exact min distances (R16: absmax 0.0).
// ---------------------------------------------------------------------------
__global__ __launch_bounds__(256) void scan_filtered_kernel(const float* __restrict__ mus,
                                                            const float* __restrict__ sigmas,
                                                            const float* __restrict__ stats,
                                                            const float* __restrict__ u0part,
                                                            float* __restrict__ partial,  // [PGRID*NB]
                                                            int Q) {
    const int b = blockIdx.x, tid = threadIdx.x;
    const int lane = tid & 63, wid = tid >> 6;

    __shared__ float2 buf[LDSCAP];
    __shared__ float  red[4][NB];
    __shared__ float  ls[4], lq[4];
    __shared__ int    cnt;

    // ---- threshold: U0 = min u0part[0..PGRID), R'^2 = max_b d^2(c0,b) ----
    {
        float u = INFINITY;
#pragma unroll
        for (int j = 0; j < PGRID / 256; ++j)
            u = fminf(u, u0part[tid + j * 256]);
        float mb0 = stats[tid], dsb = stats[NB + tid] - 1.f;
        float r2 = fmaf(mb0, mb0, dsb * dsb);
#pragma unroll
        for (int off = 32; off > 0; off >>= 1) {
            u  = fminf(u,  __shfl_down(u,  off, 64));
            r2 = fmaxf(r2, __shfl_down(r2, off, 64));
        }
        if (lane == 0) { ls[wid] = u; lq[wid] = r2; }
        if (tid == 0) cnt = 0;
    }
    __syncthreads();
    const float U0   = fminf(fminf(ls[0], ls[1]), fminf(ls[2], ls[3]));
    const float R2   = fmaxf(fmaxf(lq[0], lq[1]), fmaxf(lq[2], lq[3]));
    const float thr  = sqrtf(U0) + 2.f * sqrtf(R2);
    const float thr2 = thr * thr * 1.0001f + 1e-12f;

    // per-lane sample values (samples b = lane + 64k), direct form
    float m[4], s[4];
#pragma unroll
    for (int k = 0; k < 4; ++k) {
        m[k] = stats[lane + 64 * k];
        s[k] = stats[NB + lane + 64 * k];
    }
    float acc[4];
#pragma unroll
    for (int k = 0; k < 4; ++k) acc[k] = INFINITY;

    const int nquad = Q >> 2;
    const int spq   = (nquad + PGRID - 1) / PGRID;
    const int qs    = b * spq;
    const int qe    = min(qs + spq, nquad);
    const float4* mu4 = (const float4*)mus;
    const float4* sg4 = (const float4*)sigmas;

    // ---- filter + compact (spq<=256 -> single pass; flush kept for safety) ----
    for (int base = qs; base < qe; base += 256) {
        __syncthreads();                              // appends settled, cnt uniform
        if (cnt > LDSCAP - 1024) {
            const int n = cnt;
            for (int j = wid; j < n; j += 4) {
                float2 p = buf[j];
#pragma unroll
                for (int k = 0; k < 4; ++k) {
                    float dm = m[k] - p.x, ds = s[k] - p.y;
                    acc[k] = fminf(acc[k], fmaf(dm, dm, ds * ds));
                }
            }
            __syncthreads();
            if (tid == 0) cnt = 0;
            __syncthreads();
        }
        const int i = base + tid;
        if (i < qe) {
            float4 mu = mu4[i], sg = sg4[i];
#define TESTK(MX, SX)                                                        \
            {                                                                \
                float dm = (MX), dss = (SX) - 1.f;                           \
                float dd = fmaf(dm, dm, dss * dss);                          \
                if (dd <= thr2) {                                            \
                    int p = atomicAdd(&cnt, 1);                              \
                    buf[p] = make_float2((MX), (SX));                        \
                }                                                            \
            }
            TESTK(mu.x, sg.x)
            TESTK(mu.y, sg.y)
            TESTK(mu.z, sg.z)
            TESTK(mu.w, sg.w)
        }
    }
    if (b == 0) {                                     // element tail (empty for Q=880880)
        int q = nquad * 4 + tid;
        if (q < Q) { TESTK(mus[q], sigmas[q]) }
    }
#undef TESTK

    // final flush: direct-form scan of survivors
    __syncthreads();
    {
        const int n = cnt;
        for (int j = wid; j < n; j += 4) {
            float2 p = buf[j];
#pragma unroll
            for (int k = 0; k < 4; ++k) {
                float dm = m[k] - p.x, ds = s[k] - p.y;
                acc[k] = fminf(acc[k], fmaf(dm, dm, ds * ds));
            }
        }
    }

    // merge 4 waves, write private partial row (coalesced 1KB line writes)
    __syncthreads();
#pragma unroll
    for (int k = 0; k < 4; ++k) red[wid][lane + 64 * k] = acc[k];
    __syncthreads();
    {
        float v = fminf(fminf(red[0][tid], red[1][tid]), fminf(red[2][tid], red[3][tid]));
        partial[(size_t)b * NB + tid] = v;            // already >= 0 (direct form)
    }
}

// ---------------------------------------------------------------------------
// K3 (NB blocks): block b = sample b; min over PGRID partials (8 per thread,
// stride 1KB -- lines shared across the 16 neighboring-b blocks, L2-amortized)
// + fused T = exp(-k*sqrt(d2)).
// ---------------------------------------------------------------------------
__global__ __launch_bounds__(256) void reduce_kernel(const float* __restrict__ partial,
                                                     float* __restrict__ out) {
    const int b = blockIdx.x, tid = threadIdx.x;
    const int lane = tid & 63, wid = tid >> 6;
    __shared__ float w[4];

    float v = INFINITY;
#pragma unroll
    for (int j = 0; j < PGRID / 256; ++j)
        v = fminf(v, partial[(size_t)(tid + j * 256) * NB + b]);
#pragma unroll
    for (int off = 32; off > 0; off >>= 1)
        v = fminf(v, __shfl_down(v, off, 64));
    if (lane == 0) w[wid] = v;
    __syncthreads();
    if (tid == 0) {
        float mn = fminf(fminf(w[0], w[1]), fminf(w[2], w[3]));
        out[b] = expf(-T_K * sqrtf(fmaxf(mn, 0.f)));
    }
}

extern "C" void kernel_launch(void* const* d_in, const int* in_sizes, int n_in,
                              void* d_out, int out_size, void* d_ws, size_t ws_size,
                              hipStream_t stream) {
    const float* features = (const float*)d_in[0];
    // d_in[1]=labels, d_in[2]=pred, d_in[3]=confidence -- unused by reference
    const float* queue_mus    = (const float*)d_in[4];
    const float* queue_sigmas = (const float*)d_in[5];
    const int Q = in_sizes[4];

    float* stats   = (float*)d_ws;                 // 2*NB floats
    float* u0part  = stats + 2 * NB;               // PGRID floats
    float* partial = u0part + PGRID;               // PGRID*NB floats (2 MB)

    stats_probe_kernel<<<PGRID, 256, 0, stream>>>(features, queue_mus, queue_sigmas,
                                                  stats, u0part, Q);
    scan_filtered_kernel<<<PGRID, 256, 0, stream>>>(queue_mus, queue_sigmas, stats,
                                                    u0part, partial, Q);
    reduce_kernel<<<NB, 256, 0, stream>>>(partial, (float*)d_out);
}

// Round 18
// 17.333 us; speedup vs baseline: 2.1496x; 1.2995x over previous
//
#include <hip/hip_runtime.h>
#include <math.h>

#define NB 256
#define ND 2048
#define T_K 10.0f
#define PGRID 1024        // K1 probe grid: 4 blocks/CU -> in-flight-limited stream x4
#define SBLK 512          // K2 scan grid (R13-proven); partial = 512KB
#define LDSCAP 2048       // compaction capacity (float2 = 16 KB LDS)

// ---------------------------------------------------------------------------
// K1 (PGRID blocks): blocks 0..255 compute stats row b; ALL blocks probe
// their queue sub-chunk (min d^2(c0,q), c0=(0,1)) -> u0part[b].
// R13's K1 probed at 256 blocks = 1 wave/SIMD = in-flight-limited ~1.5TB/s
// (~5us); 1024 blocks cuts that 4x. K2/K3 stay at R13's proven shape
// (R17 lesson: 2048-block variants + 2MB partial matrix regressed).
// No global atomics anywhere (R16: one contended line = 2x + 20ms outliers).
// ---------------------------------------------------------------------------
__global__ __launch_bounds__(256) void stats_probe_kernel(const float* __restrict__ feat,
                                                          const float* __restrict__ mus,
                                                          const float* __restrict__ sigmas,
                                                          float* __restrict__ stats,
                                                          float* __restrict__ u0part,
                                                          int Q) {
    const int b = blockIdx.x, tid = threadIdx.x;
    const int lane = tid & 63, wid = tid >> 6;
    __shared__ float ls[4], lq[4];

    // ---- stats for feature row b (blocks 0..255 only; block-uniform branch) ----
    if (b < NB) {
        const float4* row = (const float4*)(feat + (size_t)b * ND);
        float sum = 0.f, sumsq = 0.f;
#pragma unroll
        for (int i = 0; i < 2; ++i) {
            float4 v = row[tid + i * 256];
            sum   += v.x + v.y + v.z + v.w;
            sumsq += v.x * v.x + v.y * v.y + v.z * v.z + v.w * v.w;
        }
#pragma unroll
        for (int off = 32; off > 0; off >>= 1) {
            sum   += __shfl_down(sum, off, 64);
            sumsq += __shfl_down(sumsq, off, 64);
        }
        if (lane == 0) { ls[wid] = sum; lq[wid] = sumsq; }
        __syncthreads();
        if (tid == 0) {
            float S  = ls[0] + ls[1] + ls[2] + ls[3];
            float Q2 = lq[0] + lq[1] + lq[2] + lq[3];
            float mean = S / (float)ND;
            float var  = fmaxf((Q2 - S * mean) / (float)(ND - 1), 0.f);
            stats[b]      = mean;
            stats[NB + b] = sqrtf(var);
        }
        __syncthreads();            // ls/lq reused by probe reduce below
    }

    // ---- probe sub-chunk b ----
    const int nquad = Q >> 2;
    const int spq   = (nquad + PGRID - 1) / PGRID;
    const int qs    = b * spq;
    const int qe    = min(qs + spq, nquad);
    const float4* mu4 = (const float4*)mus;
    const float4* sg4 = (const float4*)sigmas;

    float best = INFINITY;
    for (int i = qs + tid; i < qe; i += 256) {
        float4 mu = mu4[i], sg = sg4[i];
        float s0 = sg.x - 1.f, s1 = sg.y - 1.f, s2e = sg.z - 1.f, s3 = sg.w - 1.f;
        best = fminf(best, fmaf(mu.x, mu.x, s0 * s0));
        best = fminf(best, fmaf(mu.y, mu.y, s1 * s1));
        best = fminf(best, fmaf(mu.z, mu.z, s2e * s2e));
        best = fminf(best, fmaf(mu.w, mu.w, s3 * s3));
    }
    if (b == 0) {                   // element tail (Q % 4)
        int q = nquad * 4 + tid;
        if (q < Q) {
            float dm = mus[q], ds = sigmas[q] - 1.f;
            best = fminf(best, fmaf(dm, dm, ds * ds));
        }
    }
#pragma unroll
    for (int off = 32; off > 0; off >>= 1)
        best = fminf(best, __shfl_down(best, off, 64));
    if (lane == 0) ls[wid] = best;
    __syncthreads();
    if (tid == 0)
        u0part[b] = fminf(fminf(ls[0], ls[1]), fminf(ls[2], ls[3]));
}

// ---------------------------------------------------------------------------
// K2 (SBLK blocks): in-block threshold reduce (u0part[PGRID] + stats, L2-hot)
// -> grid-stride filter -> LDS-compact survivors -> direct-form broadcast
// scan -> PRIVATE partial row (coalesced, atomic-free).
// Exact bound: q prunable if d(c0,q) > U0 + 2R'; the global winner q* always
// survives and beats q for every sample (triangle ineq). thr^2 inflated 1e-4
// for fp32 rounding. Direct (m-mu)^2+(s-sg)^2 on survivors -> bit-exact
// min distances (R16/R17: absmax 0.0).
// ---------------------------------------------------------------------------
__global__ __launch_bounds__(256) void scan_filtered_kernel(const float* __restrict__ mus,
                                                            const float* __restrict__ sigmas,
                                                            const float* __restrict__ stats,
                                                            const float* __restrict__ u0part,
                                                            float* __restrict__ partial,  // [SBLK*NB]
                                                            int Q) {
    const int b = blockIdx.x, tid = threadIdx.x;
    const int lane = tid & 63, wid = tid >> 6;

    __shared__ float2 buf[LDSCAP];
    __shared__ float  red[4][NB];
    __shared__ float  ls[4], lq[4];
    __shared__ int    cnt;

    // ---- threshold: U0 = min u0part[0..PGRID), R'^2 = max_b d^2(c0,b) ----
    {
        float u = INFINITY;
#pragma unroll
        for (int j = 0; j < PGRID / 256; ++j)
            u = fminf(u, u0part[tid + j * 256]);
        float mb0 = stats[tid], dsb = stats[NB + tid] - 1.f;
        float r2 = fmaf(mb0, mb0, dsb * dsb);
#pragma unroll
        for (int off = 32; off > 0; off >>= 1) {
            u  = fminf(u,  __shfl_down(u,  off, 64));
            r2 = fmaxf(r2, __shfl_down(r2, off, 64));
        }
        if (lane == 0) { ls[wid] = u; lq[wid] = r2; }
        if (tid == 0) cnt = 0;
    }
    __syncthreads();
    const float U0   = fminf(fminf(ls[0], ls[1]), fminf(ls[2], ls[3]));
    const float R2   = fmaxf(fmaxf(lq[0], lq[1]), fmaxf(lq[2], lq[3]));
    const float thr  = sqrtf(U0) + 2.f * sqrtf(R2);
    const float thr2 = thr * thr * 1.0001f + 1e-12f;

    // per-lane sample values (samples b = lane + 64k), direct form
    float m[4], s[4];
#pragma unroll
    for (int k = 0; k < 4; ++k) {
        m[k] = stats[lane + 64 * k];
        s[k] = stats[NB + lane + 64 * k];
    }
    float acc[4];
#pragma unroll
    for (int k = 0; k < 4; ++k) acc[k] = INFINITY;

    const int nquad = Q >> 2;
    const float4* mu4 = (const float4*)mus;
    const float4* sg4 = (const float4*)sigmas;

    // ---- grid-stride filter + compact + flush-scan (R13 shape) ----
    for (int cb = b * 256; cb < nquad; cb += SBLK * 256) {
        __syncthreads();                              // appends settled, cnt uniform
        if (cnt > LDSCAP - 1024) {
            const int n = cnt;
            for (int j = wid; j < n; j += 4) {
                float2 p = buf[j];
#pragma unroll
                for (int k = 0; k < 4; ++k) {
                    float dm = m[k] - p.x, ds = s[k] - p.y;
                    acc[k] = fminf(acc[k], fmaf(dm, dm, ds * ds));
                }
            }
            __syncthreads();
            if (tid == 0) cnt = 0;
            __syncthreads();
        }
        const int i = cb + tid;
        if (i < nquad) {
            float4 mu = mu4[i], sg = sg4[i];
#define TESTK(MX, SX)                                                        \
            {                                                                \
                float dm = (MX), dss = (SX) - 1.f;                           \
                float dd = fmaf(dm, dm, dss * dss);                          \
                if (dd <= thr2) {                                            \
                    int p = atomicAdd(&cnt, 1);                              \
                    buf[p] = make_float2((MX), (SX));                        \
                }                                                            \
            }
            TESTK(mu.x, sg.x)
            TESTK(mu.y, sg.y)
            TESTK(mu.z, sg.z)
            TESTK(mu.w, sg.w)
        }
    }
    if (b == 0) {                                     // element tail (empty for Q=880880)
        int q = nquad * 4 + tid;
        if (q < Q) { TESTK(mus[q], sigmas[q]) }
    }
#undef TESTK

    // final flush: direct-form scan of survivors
    __syncthreads();
    {
        const int n = cnt;
        for (int j = wid; j < n; j += 4) {
            float2 p = buf[j];
#pragma unroll
            for (int k = 0; k < 4; ++k) {
                float dm = m[k] - p.x, ds = s[k] - p.y;
                acc[k] = fminf(acc[k], fmaf(dm, dm, ds * ds));
            }
        }
    }

    // merge 4 waves, write private partial row (coalesced 1KB line writes)
    __syncthreads();
#pragma unroll
    for (int k = 0; k < 4; ++k) red[wid][lane + 64 * k] = acc[k];
    __syncthreads();
    {
        float v = fminf(fminf(red[0][tid], red[1][tid]), fminf(red[2][tid], red[3][tid]));
        partial[(size_t)b * NB + tid] = v;            // >= 0 (direct form)
    }
}

// ---------------------------------------------------------------------------
// K3 (NB blocks): block b = sample b; min over SBLK partials (2 per thread)
// + fused T = exp(-k*sqrt(d2)).
// ---------------------------------------------------------------------------
__global__ __launch_bounds__(256) void reduce_kernel(const float* __restrict__ partial,
                                                     float* __restrict__ out) {
    const int b = blockIdx.x, tid = threadIdx.x;
    const int lane = tid & 63, wid = tid >> 6;
    __shared__ float w[4];

    float v = INFINITY;
#pragma unroll
    for (int j = 0; j < SBLK / 256; ++j)
        v = fminf(v, partial[(size_t)(tid + j * 256) * NB + b]);
#pragma unroll
    for (int off = 32; off > 0; off >>= 1)
        v = fminf(v, __shfl_down(v, off, 64));
    if (lane == 0) w[wid] = v;
    __syncthreads();
    if (tid == 0) {
        float mn = fminf(fminf(w[0], w[1]), fminf(w[2], w[3]));
        out[b] = expf(-T_K * sqrtf(fmaxf(mn, 0.f)));
    }
}

extern "C" void kernel_launch(void* const* d_in, const int* in_sizes, int n_in,
                              void* d_out, int out_size, void* d_ws, size_t ws_size,
                              hipStream_t stream) {
    const float* features = (const float*)d_in[0];
    // d_in[1]=labels, d_in[2]=pred, d_in[3]=confidence -- unused by reference
    const float* queue_mus    = (const float*)d_in[4];
    const float* queue_sigmas = (const float*)d_in[5];
    const int Q = in_sizes[4];

    float* stats   = (float*)d_ws;                 // 2*NB floats
    float* u0part  = stats + 2 * NB;               // PGRID floats
    float* partial = u0part + PGRID;               // SBLK*NB floats (512 KB)

    stats_probe_kernel<<<PGRID, 256, 0, stream>>>(features, queue_mus, queue_sigmas,
                                                  stats, u0part, Q);
    scan_filtered_kernel<<<SBLK, 256, 0, stream>>>(queue_mus, queue_sigmas, stats,
                                                   u0part, partial, Q);
    reduce_kernel<<<NB, 256, 0, stream>>>(partial, (float*)d_out);
}